// Round 1
// baseline (268.327 us; speedup 1.0000x reference)
//
#include <hip/hip_runtime.h>

typedef unsigned short u16;
typedef unsigned int u32;
typedef __bf16 bf16x8 __attribute__((ext_vector_type(8)));
typedef float f32x4 __attribute__((ext_vector_type(4)));

#define L_SEQ 2048
#define NH 16
#define DH 64
#define D_MODEL 1024

__device__ __forceinline__ u16 f2bf(float f) {
  union { float f; u32 u; } v; v.f = f;
  u32 u = v.u;
  return (u16)((u + 0x7fffu + ((u >> 16) & 1u)) >> 16);  // RNE
}
__device__ __forceinline__ float bf2f(u16 b) {
  union { u32 u; float f; } v; v.u = ((u32)b) << 16;
  return v.f;
}
__device__ __forceinline__ bf16x8 ld8(const u16* p) {
  union { uint4 u; bf16x8 b; } v;
  v.u = *(const uint4*)p;
  return v.b;
}
__device__ __forceinline__ f32x4 fzero4() { f32x4 z = {0.f, 0.f, 0.f, 0.f}; return z; }

// ---------------- K1: fp32 -> bf16 cast ----------------
__global__ __launch_bounds__(256) void cvt_bf16(const float* __restrict__ src,
                                                u16* __restrict__ dst, int n4) {
  int i = blockIdx.x * 256 + threadIdx.x;
  if (i >= n4) return;
  float4 v = ((const float4*)src)[i];
  ushort4 o = make_ushort4(f2bf(v.x), f2bf(v.y), f2bf(v.z), f2bf(v.w));
  ((ushort4*)dst)[i] = o;
}

// ---------------- K2/K6: bf16 GEMM, C[M,N] = A[M,K] * B[N,K]^T ----------------
// 128x128 tile, BK=64, 4 waves in 2x2, 16x16x32 MFMA, XOR-swizzled LDS (2-way max).
template <bool OUT_BF16>
__global__ __launch_bounds__(256) void gemm_bt(const u16* __restrict__ A,
                                               const u16* __restrict__ B,
                                               void* __restrict__ Cp,
                                               int N, int K) {
  __shared__ u16 As[128 * 64];
  __shared__ u16 Bs[128 * 64];
  const int t = threadIdx.x;
  const int lane = t & 63, wv = t >> 6;
  const int col = lane & 15, quad = lane >> 4;
  const int wr = wv >> 1, wc = wv & 1;
  const int m0 = blockIdx.y * 128, n0 = blockIdx.x * 128;

  f32x4 acc[4][4];
#pragma unroll
  for (int i = 0; i < 4; ++i)
#pragma unroll
    for (int j = 0; j < 4; ++j) acc[i][j] = fzero4();

  for (int kt = 0; kt < K; kt += 64) {
    __syncthreads();
#pragma unroll
    for (int it = 0; it < 4; ++it) {
      int id = it * 256 + t;
      int row = id >> 3, cs = id & 7;
      int csrc = cs ^ (row & 7);  // swizzle: LDS chunk cs holds global chunk csrc
      ((uint4*)As)[id] = *(const uint4*)(A + (size_t)(m0 + row) * K + kt + csrc * 8);
      ((uint4*)Bs)[id] = *(const uint4*)(B + (size_t)(n0 + row) * K + kt + csrc * 8);
    }
    __syncthreads();
#pragma unroll
    for (int c = 0; c < 2; ++c) {
      bf16x8 af[4], bfv[4];
#pragma unroll
      for (int f = 0; f < 4; ++f) {
        int r = wr * 64 + f * 16 + col;
        af[f] = ld8(&As[(r * 8 + ((c * 4 + quad) ^ (r & 7))) * 8]);
        int rb = wc * 64 + f * 16 + col;
        bfv[f] = ld8(&Bs[(rb * 8 + ((c * 4 + quad) ^ (rb & 7))) * 8]);
      }
#pragma unroll
      for (int i = 0; i < 4; ++i)
#pragma unroll
        for (int j = 0; j < 4; ++j)
          acc[i][j] = __builtin_amdgcn_mfma_f32_16x16x32_bf16(af[i], bfv[j], acc[i][j], 0, 0, 0);
    }
  }
#pragma unroll
  for (int i = 0; i < 4; ++i) {
    int gr = m0 + wr * 64 + i * 16 + quad * 4;
#pragma unroll
    for (int j = 0; j < 4; ++j) {
      int gc = n0 + wc * 64 + j * 16 + col;
#pragma unroll
      for (int r = 0; r < 4; ++r) {
        if (OUT_BF16)
          ((u16*)Cp)[(size_t)(gr + r) * N + gc] = f2bf(acc[i][j][r]);
        else
          ((float*)Cp)[(size_t)(gr + r) * N + gc] = acc[i][j][r];
      }
    }
  }
}

// ---------------- K3: RMSNorm + RoPE for q,k; one wave per (b,l,h) ----------------
// Also folds softmax scale 1/sqrt(64)=0.125 into q (exact in bf16).
__global__ __launch_bounds__(256) void qk_norm_rope(const u16* __restrict__ qkvb,
                                                    const float* __restrict__ rope,
                                                    const float* __restrict__ qw,
                                                    const float* __restrict__ kw,
                                                    u16* __restrict__ qb,
                                                    u16* __restrict__ kb) {
  const int t = threadIdx.x;
  const int lane = t & 63, wv = t >> 6;
  const int gid = blockIdx.x * 4 + wv;  // [0, B*L*H)
  const int bl = gid >> 4;              // b*L + l
  const int h = gid & 15;
  const int l = bl & (L_SEQ - 1);
  const int b = bl >> 11;

  size_t base = (size_t)bl * 3072 + h * 64 + lane;
  float qv = bf2f(qkvb[base]);
  float kv = bf2f(qkvb[base + 1024]);
  float sq = qv * qv, sk = kv * kv;
#pragma unroll
  for (int off = 32; off; off >>= 1) {
    sq += __shfl_xor(sq, off);
    sk += __shfl_xor(sk, off);
  }
  qv *= rsqrtf(sq * (1.f / 64.f) + 1e-6f) * qw[lane];
  kv *= rsqrtf(sk * (1.f / 64.f) + 1e-6f) * kw[lane];

  int i = lane >> 1;
  float cs = rope[((size_t)l * 32 + i) * 2 + 0];
  float sn = rope[((size_t)l * 32 + i) * 2 + 1];
  float pq = __shfl_xor(qv, 1), pk = __shfl_xor(kv, 1);
  float rq, rk;
  if (lane & 1) {
    rq = pq * sn + qv * cs;   // out_odd = even*sin + odd*cos
    rk = pk * sn + kv * cs;
  } else {
    rq = qv * cs - pq * sn;   // out_even = even*cos - odd*sin
    rk = kv * cs - pk * sn;
  }
  size_t oi = ((size_t)(b * NH + h) * L_SEQ + l) * 64 + lane;
  qb[oi] = f2bf(rq * 0.125f);
  kb[oi] = f2bf(rk);
}

// ---------------- K4: V -> V^T (B,H,Dh,L) via LDS tile ----------------
__global__ __launch_bounds__(256) void v_transpose(const u16* __restrict__ qkvb,
                                                   u16* __restrict__ vtb) {
  __shared__ u16 ldsT[64 * 65];
  const int t = threadIdx.x;
  const int bid = blockIdx.x;
  const int bh = bid >> 5;          // b*H + h
  const int l0 = (bid & 31) * 64;
  const int b = bh >> 4, h = bh & 15;
#pragma unroll
  for (int it = 0; it < 16; ++it) {
    int id = it * 256 + t;
    int ll = id >> 6, dh = id & 63;
    ldsT[dh * 65 + ll] =
        qkvb[(size_t)(b * L_SEQ + l0 + ll) * 3072 + 2048 + h * 64 + dh];
  }
  __syncthreads();
#pragma unroll
  for (int it = 0; it < 16; ++it) {
    int id = it * 256 + t;
    int dh = id >> 6, ll = id & 63;
    vtb[((size_t)bh * 64 + dh) * L_SEQ + l0 + ll] = ldsT[dh * 65 + ll];
  }
}

// ---------------- K5: flash attention ----------------
// Block: one (b,h), 64 Q rows (16/wave). Key tiles of 64. Online softmax.
__global__ __launch_bounds__(256) void attn_flash(const u16* __restrict__ qb,
                                                  const u16* __restrict__ kb,
                                                  const u16* __restrict__ vtb,
                                                  u16* __restrict__ ob) {
  __shared__ u16 ldsK[64 * 64];      // [key][dh], 16B-chunk XOR swizzled
  __shared__ u16 ldsV[64 * 64];      // [dh][key], swizzled
  __shared__ u16 ldsP[4 * 16 * 72];  // per-wave P, padded rows (+8)
  const int t = threadIdx.x;
  const int lane = t & 63, wv = t >> 6;
  const int col = lane & 15, quad = lane >> 4;
  const int bh = blockIdx.x;         // b*H + h
  const int q0 = blockIdx.y * 64;
  const int b = bh >> 4, h = bh & 15;

  const u16* qrow = qb + ((size_t)bh * L_SEQ + q0 + wv * 16 + col) * DH;
  bf16x8 qf0 = ld8(qrow + quad * 8);
  bf16x8 qf1 = ld8(qrow + 32 + quad * 8);

  f32x4 o[4];
#pragma unroll
  for (int n = 0; n < 4; ++n) o[n] = fzero4();
  float mrow[4] = {-1e30f, -1e30f, -1e30f, -1e30f};
  float lrow[4] = {0.f, 0.f, 0.f, 0.f};

  for (int kt = 0; kt < L_SEQ; kt += 64) {
    __syncthreads();
#pragma unroll
    for (int it = 0; it < 2; ++it) {
      int id = it * 256 + t;
      int row = id >> 3, cs = id & 7;
      int csrc = cs ^ (row & 7);
      ((uint4*)ldsK)[id] =
          *(const uint4*)(kb + ((size_t)bh * L_SEQ + kt + row) * DH + csrc * 8);
      ((uint4*)ldsV)[id] =
          *(const uint4*)(vtb + ((size_t)bh * DH + row) * L_SEQ + kt + csrc * 8);
    }
    __syncthreads();

    // S = Q K^T (scale already folded into q)
    f32x4 s[4];
#pragma unroll
    for (int cf = 0; cf < 4; ++cf) s[cf] = fzero4();
#pragma unroll
    for (int c = 0; c < 2; ++c) {
      bf16x8 qf = c ? qf1 : qf0;
#pragma unroll
      for (int cf = 0; cf < 4; ++cf) {
        int kr = cf * 16 + col;
        bf16x8 bfv = ld8(&ldsK[(kr * 8 + ((c * 4 + quad) ^ (kr & 7))) * 8]);
        s[cf] = __builtin_amdgcn_mfma_f32_16x16x32_bf16(qf, bfv, s[cf], 0, 0, 0);
      }
    }

    // online softmax (row = quad*4+r across 16 lanes of the quad)
    float tm[4], ts[4], al[4];
#pragma unroll
    for (int r = 0; r < 4; ++r)
      tm[r] = fmaxf(fmaxf(s[0][r], s[1][r]), fmaxf(s[2][r], s[3][r]));
    const int offs[4] = {1, 2, 4, 8};
#pragma unroll
    for (int oi = 0; oi < 4; ++oi)
#pragma unroll
      for (int r = 0; r < 4; ++r) tm[r] = fmaxf(tm[r], __shfl_xor(tm[r], offs[oi]));
#pragma unroll
    for (int r = 0; r < 4; ++r) {
      float mn = fmaxf(mrow[r], tm[r]);
      al[r] = __expf(mrow[r] - mn);
      mrow[r] = mn;
    }
#pragma unroll
    for (int cf = 0; cf < 4; ++cf)
#pragma unroll
      for (int r = 0; r < 4; ++r) s[cf][r] = __expf(s[cf][r] - mrow[r]);
#pragma unroll
    for (int r = 0; r < 4; ++r) ts[r] = s[0][r] + s[1][r] + s[2][r] + s[3][r];
#pragma unroll
    for (int oi = 0; oi < 4; ++oi)
#pragma unroll
      for (int r = 0; r < 4; ++r) ts[r] += __shfl_xor(ts[r], offs[oi]);
#pragma unroll
    for (int r = 0; r < 4; ++r) lrow[r] = lrow[r] * al[r] + ts[r];
#pragma unroll
    for (int n = 0; n < 4; ++n)
#pragma unroll
      for (int r = 0; r < 4; ++r) o[n][r] *= al[r];

    // P (C-layout) -> LDS -> A-layout; wave-private region, no barrier needed
    u16* pbase = &ldsP[wv * 16 * 72];
#pragma unroll
    for (int cf = 0; cf < 4; ++cf)
#pragma unroll
      for (int r = 0; r < 4; ++r)
        pbase[(quad * 4 + r) * 72 + cf * 16 + col] = f2bf(s[cf][r]);

#pragma unroll
    for (int c = 0; c < 2; ++c) {
      bf16x8 pa = ld8(&pbase[col * 72 + c * 32 + quad * 8]);
#pragma unroll
      for (int n = 0; n < 4; ++n) {
        int vr = n * 16 + col;
        bf16x8 vb = ld8(&ldsV[(vr * 8 + ((c * 4 + quad) ^ (vr & 7))) * 8]);
        o[n] = __builtin_amdgcn_mfma_f32_16x16x32_bf16(pa, vb, o[n], 0, 0, 0);
      }
    }
  }

  float inv[4];
#pragma unroll
  for (int r = 0; r < 4; ++r) inv[r] = 1.f / lrow[r];
  size_t obase = ((size_t)b * L_SEQ + q0 + wv * 16 + quad * 4) * D_MODEL + h * 64 + col;
#pragma unroll
  for (int n = 0; n < 4; ++n)
#pragma unroll
    for (int r = 0; r < 4; ++r)
      ob[obase + (size_t)r * D_MODEL + n * 16] = f2bf(o[n][r] * inv[r]);
}

// ---------------- launcher ----------------
extern "C" void kernel_launch(void* const* d_in, const int* in_sizes, int n_in,
                              void* d_out, int out_size, void* d_ws, size_t ws_size,
                              hipStream_t stream) {
  const float* x     = (const float*)d_in[0];
  const float* rope  = (const float*)d_in[1];
  const float* wqkv  = (const float*)d_in[2];
  const float* wproj = (const float*)d_in[3];
  const float* qnw   = (const float*)d_in[4];
  const float* knw   = (const float*)d_in[5];
  float* out = (float*)d_out;
  char* ws = (char*)d_ws;

  // workspace layout (64 MB total); ob aliases xb (x dead after GEMM1)
  u16* xb     = (u16*)(ws + 0);          //  8 MB  bf16 x (4096x1024)
  u16* wqkvb  = (u16*)(ws + 8388608);    //  6 MB  bf16 w_qkv (3072x1024)
  u16* wprojb = (u16*)(ws + 14680064);   //  2 MB  bf16 w_proj (1024x1024)
  u16* qkvb   = (u16*)(ws + 16777216);   // 24 MB  bf16 qkv (4096x3072)
  u16* qb     = (u16*)(ws + 41943040);   //  8 MB  bf16 q (B,H,L,Dh), pre-scaled
  u16* kb     = (u16*)(ws + 50331648);   //  8 MB  bf16 k (B,H,L,Dh)
  u16* vtb    = (u16*)(ws + 58720256);   //  8 MB  bf16 v^T (B,H,Dh,L)
  u16* ob     = xb;                      //  8 MB  bf16 attn out (B,L,D)

  cvt_bf16<<<4096, 256, 0, stream>>>(x, xb, 1048576);
  cvt_bf16<<<3072, 256, 0, stream>>>(wqkv, wqkvb, 786432);
  cvt_bf16<<<1024, 256, 0, stream>>>(wproj, wprojb, 262144);

  gemm_bt<true><<<dim3(24, 32), 256, 0, stream>>>(xb, wqkvb, (void*)qkvb, 3072, 1024);

  qk_norm_rope<<<16384, 256, 0, stream>>>(qkvb, rope, qnw, knw, qb, kb);
  v_transpose<<<1024, 256, 0, stream>>>(qkvb, vtb);

  attn_flash<<<dim3(32, 32), 256, 0, stream>>>(qb, kb, vtb, ob);

  gemm_bt<false><<<dim3(8, 32), 256, 0, stream>>>(ob, wprojb, (void*)out, 1024, 1024);
}

// Round 2
// 216.857 us; speedup vs baseline: 1.2373x; 1.2373x over previous
//
#include <hip/hip_runtime.h>

typedef unsigned short u16;
typedef unsigned int u32;
typedef __bf16 bf16x8 __attribute__((ext_vector_type(8)));
typedef float f32x4 __attribute__((ext_vector_type(4)));

#define L_SEQ 2048
#define NH 16
#define DH 64
#define D_MODEL 1024
#define ATT_SHIFT 10.0f

__device__ __forceinline__ u16 f2bf(float f) {
  union { float f; u32 u; } v; v.f = f;
  u32 u = v.u;
  return (u16)((u + 0x7fffu + ((u >> 16) & 1u)) >> 16);  // RNE
}
__device__ __forceinline__ float bf2f(u16 b) {
  union { u32 u; float f; } v; v.u = ((u32)b) << 16;
  return v.f;
}
// pack two floats -> two bf16 (round-half-up), lo_val in low 16 bits
__device__ __forceinline__ u32 pk2(float lo_val, float hi_val) {
  union { float f; u32 u; } a, b;
  a.f = hi_val; b.f = lo_val;
  return __builtin_amdgcn_perm(a.u + 0x8000u, b.u + 0x8000u, 0x07060302u);
}
__device__ __forceinline__ bf16x8 ld8(const u16* p) {
  union { uint4 u; bf16x8 b; } v;
  v.u = *(const uint4*)p;
  return v.b;
}
__device__ __forceinline__ f32x4 fzero4() { f32x4 z = {0.f, 0.f, 0.f, 0.f}; return z; }

// async global->LDS: lane i of the wave writes ldsbase + i*16
__device__ __forceinline__ void gll16(const u16* g, u16* l) {
  __builtin_amdgcn_global_load_lds((const __attribute__((address_space(1))) u32*)g,
                                   (__attribute__((address_space(3))) u32*)l, 16, 0, 0);
}

// ---------------- K1: fp32 -> bf16 cast ----------------
__global__ __launch_bounds__(256) void cvt_bf16(const float* __restrict__ src,
                                                u16* __restrict__ dst, int n4) {
  int i = blockIdx.x * 256 + threadIdx.x;
  if (i >= n4) return;
  float4 v = ((const float4*)src)[i];
  ushort4 o = make_ushort4(f2bf(v.x), f2bf(v.y), f2bf(v.z), f2bf(v.w));
  ((ushort4*)dst)[i] = o;
}

// ---------------- K2/K6: bf16 GEMM, C[M,N] = A[M,K] * B[N,K]^T ----------------
// 128x128 tile, BK=64, 4 waves 2x2, 16x16x32 MFMA, XOR-swizzled LDS,
// global_load_lds width-16 staging (m97 structure).
template <bool OUT_BF16>
__global__ __launch_bounds__(256) void gemm_bt(const u16* __restrict__ A,
                                               const u16* __restrict__ B,
                                               void* __restrict__ Cp,
                                               int N, int K) {
  __shared__ u16 As[128 * 64];
  __shared__ u16 Bs[128 * 64];
  const int t = threadIdx.x;
  const int lane = t & 63, wv = t >> 6;
  const int col = lane & 15, quad = lane >> 4;
  const int wr = wv >> 1, wc = wv & 1;
  const int m0 = blockIdx.y * 128, n0 = blockIdx.x * 128;

  f32x4 acc[4][4];
#pragma unroll
  for (int i = 0; i < 4; ++i)
#pragma unroll
    for (int j = 0; j < 4; ++j) acc[i][j] = fzero4();

  for (int kt = 0; kt < K; kt += 64) {
    __syncthreads();
#pragma unroll
    for (int it = 0; it < 4; ++it) {
      int id0 = it * 256 + wv * 64;     // wave-uniform LDS base (16B units)
      int id = id0 + lane;
      int row = id >> 3, cs = id & 7;
      int csrc = cs ^ (row & 7);        // swizzle: LDS chunk cs holds global chunk csrc
      gll16(A + (size_t)(m0 + row) * K + kt + csrc * 8, As + (size_t)id0 * 8);
      gll16(B + (size_t)(n0 + row) * K + kt + csrc * 8, Bs + (size_t)id0 * 8);
    }
    __syncthreads();
#pragma unroll
    for (int c = 0; c < 2; ++c) {
      bf16x8 af[4], bfv[4];
#pragma unroll
      for (int f = 0; f < 4; ++f) {
        int r = wr * 64 + f * 16 + col;
        af[f] = ld8(&As[(r * 8 + ((c * 4 + quad) ^ (r & 7))) * 8]);
        int rb = wc * 64 + f * 16 + col;
        bfv[f] = ld8(&Bs[(rb * 8 + ((c * 4 + quad) ^ (rb & 7))) * 8]);
      }
#pragma unroll
      for (int i = 0; i < 4; ++i)
#pragma unroll
        for (int j = 0; j < 4; ++j)
          acc[i][j] = __builtin_amdgcn_mfma_f32_16x16x32_bf16(af[i], bfv[j], acc[i][j], 0, 0, 0);
    }
  }
#pragma unroll
  for (int i = 0; i < 4; ++i) {
    int gr = m0 + wr * 64 + i * 16 + quad * 4;
#pragma unroll
    for (int j = 0; j < 4; ++j) {
      int gc = n0 + wc * 64 + j * 16 + col;
#pragma unroll
      for (int r = 0; r < 4; ++r) {
        if (OUT_BF16)
          ((u16*)Cp)[(size_t)(gr + r) * N + gc] = f2bf(acc[i][j][r]);
        else
          ((float*)Cp)[(size_t)(gr + r) * N + gc] = acc[i][j][r];
      }
    }
  }
}

// ---------------- K3: RMSNorm + RoPE, vectorized; one wave per (b,l) ----------------
// Folds softmax scale 0.125 into q. lane -> head group of 8 lanes, 8 elems/lane.
__global__ __launch_bounds__(256) void qk_norm_rope(const u16* __restrict__ qkvb,
                                                    const float* __restrict__ rope,
                                                    const float* __restrict__ qw,
                                                    const float* __restrict__ kw,
                                                    u16* __restrict__ qb,
                                                    u16* __restrict__ kb) {
  const int t = threadIdx.x;
  const int lane = t & 63, wv = t >> 6;
  const int gid = blockIdx.x * 4 + wv;  // b*L + l
  const int l = gid & (L_SEQ - 1);
  const int b = gid >> 11;
  const int lg = lane & 7;
  const u16* base = qkvb + (size_t)gid * 3072 + lane * 8;

  float wqv[8], wkv[8], rp[8];
  {
    float4 a = *(const float4*)(qw + lg * 8);
    float4 c = *(const float4*)(qw + lg * 8 + 4);
    wqv[0]=a.x; wqv[1]=a.y; wqv[2]=a.z; wqv[3]=a.w; wqv[4]=c.x; wqv[5]=c.y; wqv[6]=c.z; wqv[7]=c.w;
    a = *(const float4*)(kw + lg * 8);
    c = *(const float4*)(kw + lg * 8 + 4);
    wkv[0]=a.x; wkv[1]=a.y; wkv[2]=a.z; wkv[3]=a.w; wkv[4]=c.x; wkv[5]=c.y; wkv[6]=c.z; wkv[7]=c.w;
    a = *(const float4*)(rope + (size_t)l * 64 + lg * 8);
    c = *(const float4*)(rope + (size_t)l * 64 + lg * 8 + 4);
    rp[0]=a.x; rp[1]=a.y; rp[2]=a.z; rp[3]=a.w; rp[4]=c.x; rp[5]=c.y; rp[6]=c.z; rp[7]=c.w;
  }

#pragma unroll
  for (int i = 0; i < 2; ++i) {
    bf16x8 q8 = ld8(base + i * 512);
    bf16x8 k8 = ld8(base + 1024 + i * 512);
    float q[8], k[8];
#pragma unroll
    for (int j = 0; j < 8; ++j) { q[j] = (float)q8[j]; k[j] = (float)k8[j]; }
    float sq = 0.f, sk = 0.f;
#pragma unroll
    for (int j = 0; j < 8; ++j) { sq += q[j] * q[j]; sk += k[j] * k[j]; }
    sq += __shfl_xor(sq, 1); sq += __shfl_xor(sq, 2); sq += __shfl_xor(sq, 4);
    sk += __shfl_xor(sk, 1); sk += __shfl_xor(sk, 2); sk += __shfl_xor(sk, 4);
    float qi = rsqrtf(sq * (1.f / 64.f) + 1e-6f);
    float ki = rsqrtf(sk * (1.f / 64.f) + 1e-6f);

    float rq[8], rk[8];
#pragma unroll
    for (int j = 0; j < 4; ++j) {
      float cs = rp[2 * j], sn = rp[2 * j + 1];
      float qe = q[2 * j] * qi * wqv[2 * j], qo = q[2 * j + 1] * qi * wqv[2 * j + 1];
      float ke = k[2 * j] * ki * wkv[2 * j], ko = k[2 * j + 1] * ki * wkv[2 * j + 1];
      rq[2 * j]     = (qe * cs - qo * sn) * 0.125f;
      rq[2 * j + 1] = (qe * sn + qo * cs) * 0.125f;
      rk[2 * j]     = ke * cs - ko * sn;
      rk[2 * j + 1] = ke * sn + ko * cs;
    }
    uint4 qp = make_uint4(pk2(rq[0], rq[1]), pk2(rq[2], rq[3]), pk2(rq[4], rq[5]), pk2(rq[6], rq[7]));
    uint4 kp = make_uint4(pk2(rk[0], rk[1]), pk2(rk[2], rk[3]), pk2(rk[4], rk[5]), pk2(rk[6], rk[7]));
    const int head = (lane >> 3) + i * 8;
    size_t oi = (((size_t)(b * NH + head) * L_SEQ + l) * DH) + lg * 8;
    *(uint4*)(qb + oi) = qp;
    *(uint4*)(kb + oi) = kp;
  }
}

// ---------------- K4: V -> V^T (B,H,Dh,L), vectorized + swizzled LDS ----------------
__global__ __launch_bounds__(256) void v_transpose(const u16* __restrict__ qkvb,
                                                   u16* __restrict__ vtb) {
  __shared__ u16 ldsT[64 * 64];
  const int t = threadIdx.x;
  const int bid = blockIdx.x;
  const int bh = bid >> 5;
  const int lt = (bid & 31) * 64;
  const int b = bh >> 4, h = bh & 15;
  const u16* src = qkvb + (size_t)(b * L_SEQ + lt) * 3072 + 2048 + h * 64;
#pragma unroll
  for (int i = 0; i < 2; ++i) {
    int idx = i * 256 + t;
    int ll = idx >> 3, dc = idx & 7;
    uint4 v = *(const uint4*)(src + (size_t)ll * 3072 + dc * 8);
    union { uint4 u; u16 s[8]; } vv; vv.u = v;
#pragma unroll
    for (int j = 0; j < 8; ++j) {
      int dh = dc * 8 + j;
      ldsT[dh * 64 + ((((ll >> 3) ^ (dh >> 3)) & 7) * 8 + (ll & 7))] = vv.s[j];
    }
  }
  __syncthreads();
#pragma unroll
  for (int i = 0; i < 2; ++i) {
    int idx = i * 256 + t;
    int dh = idx >> 3, lc = idx & 7;
    uint4 v = *(const uint4*)&ldsT[dh * 64 + (((lc ^ (dh >> 3)) & 7) * 8)];
    *(uint4*)(vtb + ((size_t)bh * 64 + dh) * L_SEQ + lt + lc * 8) = v;
  }
}

// ---------------- K5: flash attention, S^T form, fixed softmax shift ----------------
// Block: one (b,h) x 128 q rows; wave handles 32 q rows (2 frags). 64-key tiles,
// double-buffered global_load_lds staging (prefetch issued after barrier).
__global__ __launch_bounds__(256) void attn_flash(const u16* __restrict__ qb,
                                                  const u16* __restrict__ kb,
                                                  const u16* __restrict__ vtb,
                                                  u16* __restrict__ ob) {
  __shared__ u16 ldsK[2 * 4096];     // [buf][key][dh], 16B-chunk XOR swizzled
  __shared__ u16 ldsV[2 * 4096];     // [buf][dh][key], swizzled
  __shared__ u16 ldsP[4 * 32 * 72];  // per-wave P: 32 q-rows x 64 keys (+pad), mf-XOR swizzled
  const int t = threadIdx.x;
  const int lane = t & 63, wv = t >> 6;
  const int col = lane & 15, quad = lane >> 4;
  const int bh = blockIdx.x;
  const int q0 = blockIdx.y * 128 + wv * 32;
  const int b = bh >> 4, h = bh & 15;

  const u16* kbase = kb + (size_t)bh * L_SEQ * DH;
  const u16* vbase = vtb + (size_t)bh * DH * L_SEQ;

  bf16x8 qfrag[2][2];
#pragma unroll
  for (int qf = 0; qf < 2; ++qf)
#pragma unroll
    for (int c = 0; c < 2; ++c)
      qfrag[qf][c] = ld8(qb + ((size_t)bh * L_SEQ + q0 + qf * 16 + col) * DH + c * 32 + quad * 8);

  f32x4 o[2][4];
#pragma unroll
  for (int qf = 0; qf < 2; ++qf)
#pragma unroll
    for (int nf = 0; nf < 4; ++nf) o[qf][nf] = fzero4();
  float lrow[2] = {0.f, 0.f};

  // stage tile 0 into buffer 0
#pragma unroll
  for (int it = 0; it < 2; ++it) {
    int id0 = it * 256 + wv * 64;
    int id = id0 + lane;
    int row = id >> 3, cs = id & 7, csrc = cs ^ (row & 7);
    gll16(kbase + row * DH + csrc * 8, ldsK + (size_t)id0 * 8);
    gll16(vbase + (size_t)row * L_SEQ + csrc * 8, ldsV + (size_t)id0 * 8);
  }

  u16* pb = &ldsP[wv * 32 * 72];

  for (int tt = 0; tt < 32; ++tt) {
    __syncthreads();  // compiler's vmcnt(0) drain waits for tile tt's loads (issued last iter)
    const int cur = (tt & 1) * 4096;
    if (tt + 1 < 32) {
      const int nxt = ((tt + 1) & 1) * 4096;
      const int kt = (tt + 1) * 64;
#pragma unroll
      for (int it = 0; it < 2; ++it) {
        int id0 = it * 256 + wv * 64;
        int id = id0 + lane;
        int row = id >> 3, cs = id & 7, csrc = cs ^ (row & 7);
        gll16(kbase + (size_t)(kt + row) * DH + csrc * 8, ldsK + nxt + (size_t)id0 * 8);
        gll16(vbase + (size_t)row * L_SEQ + kt + csrc * 8, ldsV + nxt + (size_t)id0 * 8);
      }
    }

    // S^T = K Q^T : rows = keys (quad*4+r + mf*16), cols = q (col)
    f32x4 s[2][4];
#pragma unroll
    for (int qf = 0; qf < 2; ++qf)
#pragma unroll
      for (int mf = 0; mf < 4; ++mf) s[qf][mf] = fzero4();
#pragma unroll
    for (int c = 0; c < 2; ++c) {
#pragma unroll
      for (int mf = 0; mf < 4; ++mf) {
        int kr = mf * 16 + col;
        bf16x8 kf = ld8(&ldsK[cur + kr * 64 + (((c * 4 + quad) ^ (kr & 7)) * 8)]);
#pragma unroll
        for (int qf = 0; qf < 2; ++qf)
          s[qf][mf] = __builtin_amdgcn_mfma_f32_16x16x32_bf16(kf, qfrag[qf][c], s[qf][mf], 0, 0, 0);
      }
    }

    // softmax with fixed shift; in-lane sum over 16 keys + 2 shuffles across quads
#pragma unroll
    for (int qf = 0; qf < 2; ++qf) {
      float ts = 0.f;
#pragma unroll
      for (int mf = 0; mf < 4; ++mf)
#pragma unroll
        for (int r = 0; r < 4; ++r) {
          float e = __expf(s[qf][mf][r] - ATT_SHIFT);
          s[qf][mf][r] = e;
          ts += e;
        }
      ts += __shfl_xor(ts, 16);
      ts += __shfl_xor(ts, 32);
      lrow[qf] += ts;
      u16* prow = pb + (qf * 16 + col) * 72;
#pragma unroll
      for (int mf = 0; mf < 4; ++mf) {
        u32 lo = pk2(s[qf][mf][0], s[qf][mf][1]);
        u32 hi = pk2(s[qf][mf][2], s[qf][mf][3]);
        *(uint2*)(prow + ((mf ^ (col & 3)) * 16 + quad * 4)) = make_uint2(lo, hi);
      }
    }

    // O += P V : A = P[q][key] from LDS, B = V^T[dh][key]
#pragma unroll
    for (int c = 0; c < 2; ++c) {
      bf16x8 pa[2];
#pragma unroll
      for (int qf = 0; qf < 2; ++qf)
        pa[qf] = ld8(pb + (qf * 16 + col) * 72 +
                     (((c * 2 + (quad >> 1)) ^ (col & 3)) * 16 + (quad & 1) * 8));
#pragma unroll
      for (int nf = 0; nf < 4; ++nf) {
        int vr = nf * 16 + col;
        bf16x8 vf = ld8(&ldsV[cur + vr * 64 + (((c * 4 + quad) ^ (vr & 7)) * 8)]);
#pragma unroll
        for (int qf = 0; qf < 2; ++qf)
          o[qf][nf] = __builtin_amdgcn_mfma_f32_16x16x32_bf16(pa[qf], vf, o[qf][nf], 0, 0, 0);
      }
    }
  }

  // epilogue: normalize by l (redistribute via shfl) and store
#pragma unroll
  for (int qf = 0; qf < 2; ++qf) {
    float li = 1.f / lrow[qf];
#pragma unroll
    for (int r = 0; r < 4; ++r) {
      float lr = __shfl(li, quad * 4 + r);
      size_t orow = ((size_t)b * L_SEQ + q0 + qf * 16 + quad * 4 + r) * D_MODEL + h * 64;
#pragma unroll
      for (int nf = 0; nf < 4; ++nf)
        ob[orow + nf * 16 + col] = f2bf(o[qf][nf][r] * lr);
    }
  }
}

// ---------------- launcher ----------------
extern "C" void kernel_launch(void* const* d_in, const int* in_sizes, int n_in,
                              void* d_out, int out_size, void* d_ws, size_t ws_size,
                              hipStream_t stream) {
  const float* x     = (const float*)d_in[0];
  const float* rope  = (const float*)d_in[1];
  const float* wqkv  = (const float*)d_in[2];
  const float* wproj = (const float*)d_in[3];
  const float* qnw   = (const float*)d_in[4];
  const float* knw   = (const float*)d_in[5];
  float* out = (float*)d_out;
  char* ws = (char*)d_ws;

  // workspace layout (64 MB total); ob aliases xb (x dead after GEMM1)
  u16* xb     = (u16*)(ws + 0);          //  8 MB  bf16 x (4096x1024)
  u16* wqkvb  = (u16*)(ws + 8388608);    //  6 MB  bf16 w_qkv (3072x1024)
  u16* wprojb = (u16*)(ws + 14680064);   //  2 MB  bf16 w_proj (1024x1024)
  u16* qkvb   = (u16*)(ws + 16777216);   // 24 MB  bf16 qkv (4096x3072)
  u16* qb     = (u16*)(ws + 41943040);   //  8 MB  bf16 q (B,H,L,Dh), pre-scaled
  u16* kb     = (u16*)(ws + 50331648);   //  8 MB  bf16 k (B,H,L,Dh)
  u16* vtb    = (u16*)(ws + 58720256);   //  8 MB  bf16 v^T (B,H,Dh,L)
  u16* ob     = xb;                      //  8 MB  bf16 attn out (B,L,D)

  cvt_bf16<<<4096, 256, 0, stream>>>(x, xb, 1048576);
  cvt_bf16<<<3072, 256, 0, stream>>>(wqkv, wqkvb, 786432);
  cvt_bf16<<<1024, 256, 0, stream>>>(wproj, wprojb, 262144);

  gemm_bt<true><<<dim3(24, 32), 256, 0, stream>>>(xb, wqkvb, (void*)qkvb, 3072, 1024);

  qk_norm_rope<<<1024, 256, 0, stream>>>(qkvb, rope, qnw, knw, qb, kb);
  v_transpose<<<1024, 256, 0, stream>>>(qkvb, vtb);

  attn_flash<<<dim3(32, 16), 256, 0, stream>>>(qb, kb, vtb, ob);

  gemm_bt<false><<<dim3(8, 32), 256, 0, stream>>>(ob, wprojb, (void*)out, 1024, 1024);
}

// Round 3
// 210.018 us; speedup vs baseline: 1.2776x; 1.0326x over previous
//
#include <hip/hip_runtime.h>

typedef unsigned short u16;
typedef unsigned int u32;
typedef __bf16 bf16x8 __attribute__((ext_vector_type(8)));
typedef float f32x4 __attribute__((ext_vector_type(4)));

#define L_SEQ 2048
#define NH 16
#define DH 64
#define D_MODEL 1024
// shift in exp2 domain: 10*log2(e); q pre-scaled by 0.125*log2(e)
#define ATT_SHIFT2 14.426950408889634f

__device__ __forceinline__ u16 f2bf(float f) {
  union { float f; u32 u; } v; v.f = f;
  u32 u = v.u;
  return (u16)((u + 0x7fffu + ((u >> 16) & 1u)) >> 16);  // RNE
}
__device__ __forceinline__ float bf2f(u16 b) {
  union { u32 u; float f; } v; v.u = ((u32)b) << 16;
  return v.f;
}
// pack two floats -> two bf16 (round-half-up), lo_val in low 16 bits
__device__ __forceinline__ u32 pk2(float lo_val, float hi_val) {
  union { float f; u32 u; } a, b;
  a.f = hi_val; b.f = lo_val;
  return __builtin_amdgcn_perm(a.u + 0x8000u, b.u + 0x8000u, 0x07060302u);
}
__device__ __forceinline__ bf16x8 ld8(const u16* p) {
  union { uint4 u; bf16x8 b; } v;
  v.u = *(const uint4*)p;
  return v.b;
}
__device__ __forceinline__ f32x4 fzero4() { f32x4 z = {0.f, 0.f, 0.f, 0.f}; return z; }

__device__ __forceinline__ float fexp2(float x) {
#if __has_builtin(__builtin_amdgcn_exp2f)
  return __builtin_amdgcn_exp2f(x);
#else
  return __expf(x * 0.6931471805599453f);
#endif
}

// async global->LDS: lane i of the wave writes ldsbase + i*16
__device__ __forceinline__ void gll16(const u16* g, u16* l) {
  __builtin_amdgcn_global_load_lds((const __attribute__((address_space(1))) u32*)g,
                                   (__attribute__((address_space(3))) u32*)l, 16, 0, 0);
}

// ---------------- K1: fp32 -> bf16 cast ----------------
__global__ __launch_bounds__(256) void cvt_bf16(const float* __restrict__ src,
                                                u16* __restrict__ dst, int n4) {
  int i = blockIdx.x * 256 + threadIdx.x;
  if (i >= n4) return;
  float4 v = ((const float4*)src)[i];
  ushort4 o = make_ushort4(f2bf(v.x), f2bf(v.y), f2bf(v.z), f2bf(v.w));
  ((ushort4*)dst)[i] = o;
}

// ---------------- K2/K7: bf16 GEMM, C[M,N] = A[M,K] * B[N,K]^T ----------------
// BMx128 tile, BK=64, 4 waves 2x2, 16x16x32 MFMA, XOR-swizzled LDS,
// global_load_lds width-16 staging (m97 structure).
template <int BM, bool OUT_BF16>
__global__ __launch_bounds__(256) void gemm_bt(const u16* __restrict__ A,
                                               const u16* __restrict__ B,
                                               void* __restrict__ Cp,
                                               int N, int K) {
  constexpr int MI = BM / 32;  // m-frags per wave
  __shared__ u16 As[BM * 64];
  __shared__ u16 Bs[128 * 64];
  const int t = threadIdx.x;
  const int lane = t & 63, wv = t >> 6;
  const int col = lane & 15, quad = lane >> 4;
  const int wr = wv >> 1, wc = wv & 1;
  const int m0 = blockIdx.y * BM, n0 = blockIdx.x * 128;

  f32x4 acc[MI][4];
#pragma unroll
  for (int i = 0; i < MI; ++i)
#pragma unroll
    for (int j = 0; j < 4; ++j) acc[i][j] = fzero4();

  for (int kt = 0; kt < K; kt += 64) {
    __syncthreads();
#pragma unroll
    for (int it = 0; it < BM / 32; ++it) {
      int id0 = it * 256 + wv * 64;     // wave-uniform LDS base (16B units)
      int id = id0 + lane;
      int row = id >> 3, cs = id & 7;
      int csrc = cs ^ (row & 7);        // swizzle: LDS chunk cs holds global chunk csrc
      gll16(A + (size_t)(m0 + row) * K + kt + csrc * 8, As + (size_t)id0 * 8);
    }
#pragma unroll
    for (int it = 0; it < 4; ++it) {
      int id0 = it * 256 + wv * 64;
      int id = id0 + lane;
      int row = id >> 3, cs = id & 7;
      int csrc = cs ^ (row & 7);
      gll16(B + (size_t)(n0 + row) * K + kt + csrc * 8, Bs + (size_t)id0 * 8);
    }
    __syncthreads();
#pragma unroll
    for (int c = 0; c < 2; ++c) {
      bf16x8 af[MI], bfv[4];
#pragma unroll
      for (int f = 0; f < MI; ++f) {
        int r = wr * (BM / 2) + f * 16 + col;
        af[f] = ld8(&As[(r * 8 + ((c * 4 + quad) ^ (r & 7))) * 8]);
      }
#pragma unroll
      for (int f = 0; f < 4; ++f) {
        int rb = wc * 64 + f * 16 + col;
        bfv[f] = ld8(&Bs[(rb * 8 + ((c * 4 + quad) ^ (rb & 7))) * 8]);
      }
#pragma unroll
      for (int i = 0; i < MI; ++i)
#pragma unroll
        for (int j = 0; j < 4; ++j)
          acc[i][j] = __builtin_amdgcn_mfma_f32_16x16x32_bf16(af[i], bfv[j], acc[i][j], 0, 0, 0);
    }
  }
#pragma unroll
  for (int i = 0; i < MI; ++i) {
    int gr = m0 + wr * (BM / 2) + i * 16 + quad * 4;
#pragma unroll
    for (int j = 0; j < 4; ++j) {
      int gc = n0 + wc * 64 + j * 16 + col;
#pragma unroll
      for (int r = 0; r < 4; ++r) {
        if (OUT_BF16)
          ((u16*)Cp)[(size_t)(gr + r) * N + gc] = f2bf(acc[i][j][r]);
        else
          ((float*)Cp)[(size_t)(gr + r) * N + gc] = acc[i][j][r];
      }
    }
  }
}

// ---------------- K3: RMSNorm + RoPE, vectorized; one wave per (b,l) ----------------
// Folds softmax scale 0.125 AND log2(e) (for exp2 softmax) into q.
__global__ __launch_bounds__(256) void qk_norm_rope(const u16* __restrict__ qkvb,
                                                    const float* __restrict__ rope,
                                                    const float* __restrict__ qw,
                                                    const float* __restrict__ kw,
                                                    u16* __restrict__ qb,
                                                    u16* __restrict__ kb) {
  const int t = threadIdx.x;
  const int lane = t & 63, wv = t >> 6;
  const int gid = blockIdx.x * 4 + wv;  // b*L + l
  const int l = gid & (L_SEQ - 1);
  const int b = gid >> 11;
  const int lg = lane & 7;
  const u16* base = qkvb + (size_t)gid * 3072 + lane * 8;
  const float QSCALE = 0.125f * 1.4426950408889634f;

  float wqv[8], wkv[8], rp[8];
  {
    float4 a = *(const float4*)(qw + lg * 8);
    float4 c = *(const float4*)(qw + lg * 8 + 4);
    wqv[0]=a.x; wqv[1]=a.y; wqv[2]=a.z; wqv[3]=a.w; wqv[4]=c.x; wqv[5]=c.y; wqv[6]=c.z; wqv[7]=c.w;
    a = *(const float4*)(kw + lg * 8);
    c = *(const float4*)(kw + lg * 8 + 4);
    wkv[0]=a.x; wkv[1]=a.y; wkv[2]=a.z; wkv[3]=a.w; wkv[4]=c.x; wkv[5]=c.y; wkv[6]=c.z; wkv[7]=c.w;
    a = *(const float4*)(rope + (size_t)l * 64 + lg * 8);
    c = *(const float4*)(rope + (size_t)l * 64 + lg * 8 + 4);
    rp[0]=a.x; rp[1]=a.y; rp[2]=a.z; rp[3]=a.w; rp[4]=c.x; rp[5]=c.y; rp[6]=c.z; rp[7]=c.w;
  }

#pragma unroll
  for (int i = 0; i < 2; ++i) {
    bf16x8 q8 = ld8(base + i * 512);
    bf16x8 k8 = ld8(base + 1024 + i * 512);
    float q[8], k[8];
#pragma unroll
    for (int j = 0; j < 8; ++j) { q[j] = (float)q8[j]; k[j] = (float)k8[j]; }
    float sq = 0.f, sk = 0.f;
#pragma unroll
    for (int j = 0; j < 8; ++j) { sq += q[j] * q[j]; sk += k[j] * k[j]; }
    sq += __shfl_xor(sq, 1); sq += __shfl_xor(sq, 2); sq += __shfl_xor(sq, 4);
    sk += __shfl_xor(sk, 1); sk += __shfl_xor(sk, 2); sk += __shfl_xor(sk, 4);
    float qi = rsqrtf(sq * (1.f / 64.f) + 1e-6f);
    float ki = rsqrtf(sk * (1.f / 64.f) + 1e-6f);

    float rq[8], rk[8];
#pragma unroll
    for (int j = 0; j < 4; ++j) {
      float cs = rp[2 * j], sn = rp[2 * j + 1];
      float qe = q[2 * j] * qi * wqv[2 * j], qo = q[2 * j + 1] * qi * wqv[2 * j + 1];
      float ke = k[2 * j] * ki * wkv[2 * j], ko = k[2 * j + 1] * ki * wkv[2 * j + 1];
      rq[2 * j]     = (qe * cs - qo * sn) * QSCALE;
      rq[2 * j + 1] = (qe * sn + qo * cs) * QSCALE;
      rk[2 * j]     = ke * cs - ko * sn;
      rk[2 * j + 1] = ke * sn + ko * cs;
    }
    uint4 qp = make_uint4(pk2(rq[0], rq[1]), pk2(rq[2], rq[3]), pk2(rq[4], rq[5]), pk2(rq[6], rq[7]));
    uint4 kp = make_uint4(pk2(rk[0], rk[1]), pk2(rk[2], rk[3]), pk2(rk[4], rk[5]), pk2(rk[6], rk[7]));
    const int head = (lane >> 3) + i * 8;
    size_t oi = (((size_t)(b * NH + head) * L_SEQ + l) * DH) + lg * 8;
    *(uint4*)(qb + oi) = qp;
    *(uint4*)(kb + oi) = kp;
  }
}

// ---------------- K4: V -> V^T (B,H,Dh,L), vectorized + swizzled LDS ----------------
__global__ __launch_bounds__(256) void v_transpose(const u16* __restrict__ qkvb,
                                                   u16* __restrict__ vtb) {
  __shared__ u16 ldsT[64 * 64];
  const int t = threadIdx.x;
  const int bid = blockIdx.x;
  const int bh = bid >> 5;
  const int lt = (bid & 31) * 64;
  const int b = bh >> 4, h = bh & 15;
  const u16* src = qkvb + (size_t)(b * L_SEQ + lt) * 3072 + 2048 + h * 64;
#pragma unroll
  for (int i = 0; i < 2; ++i) {
    int idx = i * 256 + t;
    int ll = idx >> 3, dc = idx & 7;
    uint4 v = *(const uint4*)(src + (size_t)ll * 3072 + dc * 8);
    union { uint4 u; u16 s[8]; } vv; vv.u = v;
#pragma unroll
    for (int j = 0; j < 8; ++j) {
      int dh = dc * 8 + j;
      ldsT[dh * 64 + ((((ll >> 3) ^ (dh >> 3)) & 7) * 8 + (ll & 7))] = vv.s[j];
    }
  }
  __syncthreads();
#pragma unroll
  for (int i = 0; i < 2; ++i) {
    int idx = i * 256 + t;
    int dh = idx >> 3, lc = idx & 7;
    uint4 v = *(const uint4*)&ldsT[dh * 64 + (((lc ^ (dh >> 3)) & 7) * 8)];
    *(uint4*)(vtb + ((size_t)bh * 64 + dh) * L_SEQ + lt + lc * 8) = v;
  }
}

// ---------------- K5: flash attention, S^T form, fixed shift, split-K x2 ----------------
// Block: (b,h) x 128 q rows x half the keys; wave = 32 q rows. Partials (bf16 o, f32 l)
// are linearly addable thanks to the fixed shift; combine kernel merges.
__global__ __launch_bounds__(256) void attn_flash(const u16* __restrict__ qb,
                                                  const u16* __restrict__ kb,
                                                  const u16* __restrict__ vtb,
                                                  u16* __restrict__ po,
                                                  float* __restrict__ pl) {
  __shared__ u16 ldsK[2 * 4096];     // [buf][key][dh], 16B-chunk XOR swizzled
  __shared__ u16 ldsV[2 * 4096];     // [buf][dh][key], swizzled
  __shared__ u16 ldsP[4 * 32 * 72];  // per-wave P: 32 q-rows x 64 keys (+pad)
  const int t = threadIdx.x;
  const int lane = t & 63, wv = t >> 6;
  const int col = lane & 15, quad = lane >> 4;
  const int bh = blockIdx.x;
  const int q0 = blockIdx.y * 128 + wv * 32;
  const int half = blockIdx.z;

  const u16* kbase = kb + ((size_t)bh * L_SEQ + half * 1024) * DH;
  const u16* vbase = vtb + (size_t)bh * DH * L_SEQ + half * 1024;

  bf16x8 qfrag[2][2];
#pragma unroll
  for (int qf = 0; qf < 2; ++qf)
#pragma unroll
    for (int c = 0; c < 2; ++c)
      qfrag[qf][c] = ld8(qb + ((size_t)bh * L_SEQ + q0 + qf * 16 + col) * DH + c * 32 + quad * 8);

  f32x4 o[2][4];
#pragma unroll
  for (int qf = 0; qf < 2; ++qf)
#pragma unroll
    for (int nf = 0; nf < 4; ++nf) o[qf][nf] = fzero4();
  float lrow[2] = {0.f, 0.f};

  // stage tile 0 into buffer 0
#pragma unroll
  for (int it = 0; it < 2; ++it) {
    int id0 = it * 256 + wv * 64;
    int id = id0 + lane;
    int row = id >> 3, cs = id & 7, csrc = cs ^ (row & 7);
    gll16(kbase + row * DH + csrc * 8, ldsK + (size_t)id0 * 8);
    gll16(vbase + (size_t)row * L_SEQ + csrc * 8, ldsV + (size_t)id0 * 8);
  }

  u16* pb = &ldsP[wv * 32 * 72];

  for (int tt = 0; tt < 16; ++tt) {
    __syncthreads();  // vmcnt(0) drain covers tile tt's loads (issued last iter)
    const int cur = (tt & 1) * 4096;
    if (tt + 1 < 16) {
      const int nxt = ((tt + 1) & 1) * 4096;
      const int kt = (tt + 1) * 64;
#pragma unroll
      for (int it = 0; it < 2; ++it) {
        int id0 = it * 256 + wv * 64;
        int id = id0 + lane;
        int row = id >> 3, cs = id & 7, csrc = cs ^ (row & 7);
        gll16(kbase + (size_t)(kt + row) * DH + csrc * 8, ldsK + nxt + (size_t)id0 * 8);
        gll16(vbase + (size_t)row * L_SEQ + kt + csrc * 8, ldsV + nxt + (size_t)id0 * 8);
      }
    }

    // S^T = K Q^T : rows = keys (mf*16 + quad*4 + r), cols = q (col)
    f32x4 s[2][4];
#pragma unroll
    for (int qf = 0; qf < 2; ++qf)
#pragma unroll
      for (int mf = 0; mf < 4; ++mf) s[qf][mf] = fzero4();
#pragma unroll
    for (int c = 0; c < 2; ++c) {
#pragma unroll
      for (int mf = 0; mf < 4; ++mf) {
        int kr = mf * 16 + col;
        bf16x8 kf = ld8(&ldsK[cur + kr * 64 + (((c * 4 + quad) ^ (kr & 7)) * 8)]);
#pragma unroll
        for (int qf = 0; qf < 2; ++qf)
          s[qf][mf] = __builtin_amdgcn_mfma_f32_16x16x32_bf16(kf, qfrag[qf][c], s[qf][mf], 0, 0, 0);
      }
    }

    // exp2 softmax (shift folded); per-lane partial l, cross-quad reduce deferred
#pragma unroll
    for (int qf = 0; qf < 2; ++qf) {
      float ts = 0.f;
#pragma unroll
      for (int mf = 0; mf < 4; ++mf)
#pragma unroll
        for (int r = 0; r < 4; ++r) {
          float e = fexp2(s[qf][mf][r] - ATT_SHIFT2);
          s[qf][mf][r] = e;
          ts += e;
        }
      lrow[qf] += ts;
      u16* prow = pb + (qf * 16 + col) * 72;
#pragma unroll
      for (int mf = 0; mf < 4; ++mf) {
        u32 lo = pk2(s[qf][mf][0], s[qf][mf][1]);
        u32 hi = pk2(s[qf][mf][2], s[qf][mf][3]);
        *(uint2*)(prow + ((mf ^ (col & 3)) * 16 + quad * 4)) = make_uint2(lo, hi);
      }
    }

    // O += P V : A = P[q][key] from LDS, B = V^T[dh][key]
#pragma unroll
    for (int c = 0; c < 2; ++c) {
      bf16x8 pa[2];
#pragma unroll
      for (int qf = 0; qf < 2; ++qf)
        pa[qf] = ld8(pb + (qf * 16 + col) * 72 +
                     (((c * 2 + (quad >> 1)) ^ (col & 3)) * 16 + (quad & 1) * 8));
#pragma unroll
      for (int nf = 0; nf < 4; ++nf) {
        int vr = nf * 16 + col;
        bf16x8 vf = ld8(&ldsV[cur + vr * 64 + (((c * 4 + quad) ^ (vr & 7)) * 8)]);
#pragma unroll
        for (int qf = 0; qf < 2; ++qf)
          o[qf][nf] = __builtin_amdgcn_mfma_f32_16x16x32_bf16(pa[qf], vf, o[qf][nf], 0, 0, 0);
      }
    }
  }

  // epilogue: finish l reduction, write unnormalized partials
  u16* pob = po + (size_t)(half * 32 + bh) * L_SEQ * DH;
#pragma unroll
  for (int qf = 0; qf < 2; ++qf) {
    lrow[qf] += __shfl_xor(lrow[qf], 16);
    lrow[qf] += __shfl_xor(lrow[qf], 32);
    if (quad == 0)
      pl[(size_t)(half * 32 + bh) * L_SEQ + q0 + qf * 16 + col] = lrow[qf];
#pragma unroll
    for (int nf = 0; nf < 4; ++nf)
#pragma unroll
      for (int r = 0; r < 4; ++r)
        pob[(size_t)(q0 + qf * 16 + quad * 4 + r) * DH + nf * 16 + col] = f2bf(o[qf][nf][r]);
  }
}

// ---------------- K6: combine split-K partials -> ob (B,L,D) bf16 ----------------
__global__ __launch_bounds__(256) void attn_combine(const u16* __restrict__ po,
                                                    const float* __restrict__ pl,
                                                    u16* __restrict__ ob) {
  int j = blockIdx.x * 256 + threadIdx.x;  // 0 .. 512K
  int bh = j >> 14;                        // 2048*64/8 groups per bh
  int rem = j & 16383;
  int l = rem >> 3, dc = rem & 7;
  size_t pidx = ((size_t)bh * L_SEQ + l) * DH + dc * 8;
  uint4 a = *(const uint4*)(po + pidx);
  uint4 c = *(const uint4*)(po + 4194304 + pidx);
  float inv = 1.f / (pl[(size_t)bh * L_SEQ + l] + pl[65536 + (size_t)bh * L_SEQ + l]);
  union { uint4 u; u16 s[8]; } ua, uc; ua.u = a; uc.u = c;
  float r[8];
#pragma unroll
  for (int i = 0; i < 8; ++i) r[i] = (bf2f(ua.s[i]) + bf2f(uc.s[i])) * inv;
  uint4 out = make_uint4(pk2(r[0], r[1]), pk2(r[2], r[3]), pk2(r[4], r[5]), pk2(r[6], r[7]));
  int b = bh >> 4, h = bh & 15;
  *(uint4*)(ob + ((size_t)(b * L_SEQ + l)) * D_MODEL + h * 64 + dc * 8) = out;
}

// ---------------- launcher ----------------
extern "C" void kernel_launch(void* const* d_in, const int* in_sizes, int n_in,
                              void* d_out, int out_size, void* d_ws, size_t ws_size,
                              hipStream_t stream) {
  const float* x     = (const float*)d_in[0];
  const float* rope  = (const float*)d_in[1];
  const float* wqkv  = (const float*)d_in[2];
  const float* wproj = (const float*)d_in[3];
  const float* qnw   = (const float*)d_in[4];
  const float* knw   = (const float*)d_in[5];
  float* out = (float*)d_out;
  char* ws = (char*)d_ws;

  // workspace layout (64 MB); ob aliases xb; po/pl alias qkvb (dead after norm/transpose)
  u16* xb     = (u16*)(ws + 0);          //  8 MB  bf16 x (4096x1024)
  u16* wqkvb  = (u16*)(ws + 8388608);    //  6 MB  bf16 w_qkv (3072x1024)
  u16* wprojb = (u16*)(ws + 14680064);   //  2 MB  bf16 w_proj (1024x1024)
  u16* qkvb   = (u16*)(ws + 16777216);   // 24 MB  bf16 qkv (4096x3072)
  u16* qb     = (u16*)(ws + 41943040);   //  8 MB  bf16 q (B,H,L,Dh), pre-scaled
  u16* kb     = (u16*)(ws + 50331648);   //  8 MB  bf16 k (B,H,L,Dh)
  u16* vtb    = (u16*)(ws + 58720256);   //  8 MB  bf16 v^T (B,H,Dh,L)
  u16* ob     = xb;                      //  8 MB  bf16 attn out (B,L,D)
  u16* po     = qkvb;                    // 16 MB  bf16 o-partials [half][bh][q][dh]
  float* pl   = (float*)(ws + 33554432); // 512 KB f32 l-partials [half][bh][q]

  cvt_bf16<<<4096, 256, 0, stream>>>(x, xb, 1048576);
  cvt_bf16<<<3072, 256, 0, stream>>>(wqkv, wqkvb, 786432);
  cvt_bf16<<<1024, 256, 0, stream>>>(wproj, wprojb, 262144);

  gemm_bt<128, true><<<dim3(24, 32), 256, 0, stream>>>(xb, wqkvb, (void*)qkvb, 3072, 1024);

  qk_norm_rope<<<1024, 256, 0, stream>>>(qkvb, rope, qnw, knw, qb, kb);
  v_transpose<<<1024, 256, 0, stream>>>(qkvb, vtb);

  attn_flash<<<dim3(32, 16, 2), 256, 0, stream>>>(qb, kb, vtb, po, pl);
  attn_combine<<<2048, 256, 0, stream>>>(po, pl, ob);

  gemm_bt<64, false><<<dim3(8, 64), 256, 0, stream>>>(ob, wprojb, (void*)out, 1024, 1024);
}